// Round 11
// baseline (739.949 us; speedup 1.0000x reference)
//
#include <hip/hip_runtime.h>
#include <hip/hip_bf16.h>

#define DM 1024   // model dim
#define LQ 2048   // sequence length

typedef __attribute__((ext_vector_type(8))) short short8;
typedef __attribute__((ext_vector_type(4))) float floatx4;

#define MFMA16(a, b, c) __builtin_amdgcn_mfma_f32_16x16x32_bf16((a), (b), (c), 0, 0, 0)
#define BAR() __builtin_amdgcn_s_barrier()
#define FENCE() asm volatile("" ::: "memory")
#define VWAIT4() asm volatile("s_waitcnt vmcnt(4)" ::: "memory")
#define VWAIT0() asm volatile("s_waitcnt vmcnt(0)" ::: "memory")

__device__ __forceinline__ unsigned short f2b(float f) {
  union { float f; unsigned u; } x; x.f = f;
  unsigned u = x.u;
  unsigned r = (u + 0x7fffu + ((u >> 16) & 1u)) >> 16;  // RNE
  return (unsigned short)r;
}

// pack two fp32 -> bf16x2 in ONE instruction (HW RNE).
__device__ __forceinline__ unsigned cvt_pk(float lo, float hi) {
  unsigned r;
  asm("v_cvt_pk_bf16_f32 %0, %1, %2" : "=v"(r) : "v"(lo), "v"(hi));
  return r;
}
__device__ __forceinline__ uint4 pack16(float4 a, float4 b) {
  return make_uint4(cvt_pk(a.x, a.y), cvt_pk(a.z, a.w),
                    cvt_pk(b.x, b.y), cvt_pk(b.z, b.w));
}

// async global->LDS, 16B per lane; LDS dest = wave-uniform base + lane*16
__device__ __forceinline__ void gl_lds16(const void* g, void* l) {
  __builtin_amdgcn_global_load_lds(
      (const __attribute__((address_space(1))) void*)g,
      (__attribute__((address_space(3))) void*)l, 16, 0, 0);
}

// XCD-aware tile remap for 64 m-tiles x 8 n-tiles grids (gridDim.x == 8).
// r1 result: FETCH 397->82 MB (confirmed L2-reuse mechanism).
__device__ __forceinline__ void xcd_tiles(int bx, int by, int* m0, int* n0) {
  int flat = bx + (by << 3);
  int xcd = flat & 7;
  int loc = flat >> 3;
  *m0 = (xcd * 8 + (loc >> 3)) * 128;
  *n0 = (loc & 7) * 128;
}

// ---------------------------------------------------------------------------
// fp32 -> bf16 conversion of the three activation inputs (one-time pass).
// grid (4096,1,3).
// ---------------------------------------------------------------------------
__global__ __launch_bounds__(256) void cvt3(
    const float* __restrict__ A0, const float* __restrict__ A1,
    const float* __restrict__ A2,
    unsigned short* __restrict__ O0, unsigned short* __restrict__ O1,
    unsigned short* __restrict__ O2) {
  const float* s = (blockIdx.z == 0) ? A0 : (blockIdx.z == 1) ? A1 : A2;
  unsigned short* d = (blockIdx.z == 0) ? O0 : (blockIdx.z == 1) ? O1 : O2;
  size_t i = ((size_t)blockIdx.x * 256 + threadIdx.x) * 8;
  float4 f0 = *(const float4*)(s + i);
  float4 f1 = *(const float4*)(s + i + 4);
  *(uint4*)(d + i) = pack16(f0, f1);
}

// ---------------------------------------------------------------------------
// 4 weight transposes in one dispatch: dst[n][k] = bf16(src[k][n]), 1024x1024
// grid (16,16,4)
// ---------------------------------------------------------------------------
__global__ __launch_bounds__(256) void transpose_w4(
    const float* __restrict__ W0, const float* __restrict__ W1,
    const float* __restrict__ W2, const float* __restrict__ W3,
    unsigned short* __restrict__ T0, unsigned short* __restrict__ T1,
    unsigned short* __restrict__ T2, unsigned short* __restrict__ T3) {
  __shared__ unsigned short t[64][65];
  const float* src; unsigned short* dst;
  switch (blockIdx.z) {
    case 0: src = W0; dst = T0; break;
    case 1: src = W1; dst = T1; break;
    case 2: src = W2; dst = T2; break;
    default: src = W3; dst = T3; break;
  }
  const int x = threadIdx.x & 63;
  const int y4 = threadIdx.x >> 6;
  const int c0 = blockIdx.x * 64;
  const int r0 = blockIdx.y * 64;
#pragma unroll
  for (int i = 0; i < 16; ++i) {
    int r = y4 * 16 + i;
    t[r][x] = f2b(src[(size_t)(r0 + r) * 1024 + c0 + x]);
  }
  __syncthreads();
#pragma unroll
  for (int i = 0; i < 16; ++i) {
    int r = y4 * 16 + i;
    dst[(size_t)(c0 + r) * 1024 + r0 + x] = t[x][r];
  }
}

// ---------------------------------------------------------------------------
// Counted-vmcnt K-loop (T4, m218), verified r5. r4 lesson: no LDS pointer
// arrays on gfx950 — index __shared__ arrays directly.
// ---------------------------------------------------------------------------

// ---------------------------------------------------------------------------
// Batched QKV projection from PRE-CONVERTED bf16 activations.
// z=0 -> Qb (pre-scaled by log2(e)/sqrt(dk)), z=1 -> Kb, z=2 -> Vt
// (transposed layout Vt[(b*16+h)*64+d][l]).
// grid (8, 64, 3), block 256. XCD-swizzled tiles.
// ---------------------------------------------------------------------------
__global__ __launch_bounds__(256) void gemm_qkv(
    const unsigned short* __restrict__ Aq, const unsigned short* __restrict__ Ak,
    const unsigned short* __restrict__ Av,
    const unsigned short* __restrict__ BtQ, const unsigned short* __restrict__ BtK,
    const unsigned short* __restrict__ BtV,
    const float* __restrict__ bq, const float* __restrict__ bk,
    const float* __restrict__ bv,
    unsigned short* __restrict__ Qb, unsigned short* __restrict__ Kb,
    unsigned short* __restrict__ Vt) {
  const int K = 1024, N = 1024;
  __shared__ unsigned short As[2][128 * 32];
  __shared__ unsigned short Bs[2][128 * 32];
  const int z = blockIdx.z;
  const unsigned short* A; const unsigned short* Bt; const float* bias;
  if (z == 0) { A = Aq; Bt = BtQ; bias = bq; }
  else if (z == 1) { A = Ak; Bt = BtK; bias = bk; }
  else { A = Av; Bt = BtV; bias = bv; }

  const int tid = threadIdx.x;
  const int wave = tid >> 6;
  const int lane = tid & 63;
  const int fm = lane & 15;
  const int quad = lane >> 4;
  int m0, n0;
  xcd_tiles(blockIdx.x, blockIdx.y, &m0, &n0);
  const int wm = (wave >> 1) * 64;
  const int wn = (wave & 1) * 64;

  floatx4 acc[4][4];
#pragma unroll
  for (int i = 0; i < 4; ++i)
#pragma unroll
    for (int j = 0; j < 4; ++j) acc[i][j] = (floatx4){0.f, 0.f, 0.f, 0.f};

  const int srow = lane >> 2;       // 0..15
  const int scol = (lane & 3) * 8;  // 0,8,16,24 (shorts; 16B per lane)
  const unsigned short* Ag = A + (size_t)(m0 + wave * 32 + srow) * K + scol;
  const unsigned short* Bg = Bt + (size_t)(n0 + wave * 32 + srow) * K + scol;
  const int stA = wave * 32 * 32;

  // prologue: stage tiles 0 and 1 (8 loads outstanding per wave)
#pragma unroll
  for (int t = 0; t < 2; ++t) {
    gl_lds16(Ag + t * 32, &As[t][stA]);
    gl_lds16(Ag + t * 32 + (size_t)16 * K, &As[t][stA + 16 * 32]);
    gl_lds16(Bg + t * 32, &Bs[t][stA]);
    gl_lds16(Bg + t * 32 + (size_t)16 * K, &Bs[t][stA + 16 * 32]);
  }

#pragma unroll 1
  for (int t = 0; t < 30; ++t) {
    const int buf = t & 1;
    VWAIT4();            // tile t's 4 loads done; t+1's stay in flight
    BAR();
    FENCE();
    short8 a[4], b[4];
#pragma unroll
    for (int i = 0; i < 4; ++i)
      a[i] = *(const short8*)&As[buf][(wm + i * 16 + fm) * 32 + quad * 8];
#pragma unroll
    for (int j = 0; j < 4; ++j)
      b[j] = *(const short8*)&Bs[buf][(wn + j * 16 + fm) * 32 + quad * 8];
#pragma unroll
    for (int i = 0; i < 4; ++i)
#pragma unroll
      for (int j = 0; j < 4; ++j) acc[i][j] = MFMA16(a[i], b[j], acc[i][j]);
    BAR();               // all waves done reading buf
    FENCE();
    const int tn = t + 2;
    gl_lds16(Ag + tn * 32, &As[buf][stA]);
    gl_lds16(Ag + tn * 32 + (size_t)16 * K, &As[buf][stA + 16 * 32]);
    gl_lds16(Bg + tn * 32, &Bs[buf][stA]);
    gl_lds16(Bg + tn * 32 + (size_t)16 * K, &Bs[buf][stA + 16 * 32]);
  }
  // peeled tails: t=30 (buf 0), t=31 (buf 1); no more staging
#pragma unroll
  for (int t = 30; t < 32; ++t) {
    if (t == 30) VWAIT4(); else VWAIT0();
    BAR();
    FENCE();
    const int buf = t & 1;
    short8 a[4], b[4];
#pragma unroll
    for (int i = 0; i < 4; ++i)
      a[i] = *(const short8*)&As[buf][(wm + i * 16 + fm) * 32 + quad * 8];
#pragma unroll
    for (int j = 0; j < 4; ++j)
      b[j] = *(const short8*)&Bs[buf][(wn + j * 16 + fm) * 32 + quad * 8];
#pragma unroll
    for (int i = 0; i < 4; ++i)
#pragma unroll
      for (int j = 0; j < 4; ++j) acc[i][j] = MFMA16(a[i], b[j], acc[i][j]);
  }

  float bvv[4];
#pragma unroll
  for (int j = 0; j < 4; ++j) bvv[j] = bias[n0 + wn + j * 16 + fm];

  if (z < 2) {
    // Q is pre-scaled by log2(e)/sqrt(dk) so attn's exp2 needs no multiply.
    const float sc = (z == 0) ? 0.1803368801111204f : 1.0f;
    unsigned short* C = (z == 0) ? Qb : Kb;
#pragma unroll
    for (int i = 0; i < 4; ++i) {
      int row = m0 + wm + i * 16 + quad * 4;
#pragma unroll
      for (int j = 0; j < 4; ++j) {
        int col = n0 + wn + j * 16 + fm;
#pragma unroll
        for (int r = 0; r < 4; ++r)
          C[(size_t)(row + r) * N + col] = f2b((acc[i][j][r] + bvv[j]) * sc);
      }
    }
  } else {
    // transposed: Vt[((b*16+h)*64+d)][l]
#pragma unroll
    for (int i = 0; i < 4; ++i) {
      int row = m0 + wm + i * 16 + quad * 4;
      int b = row >> 11, l = row & 2047;
#pragma unroll
      for (int j = 0; j < 4; ++j) {
        int col = n0 + wn + j * 16 + fm;
        int h = col >> 6, d = col & 63;
        uint2 pk;
        pk.x = cvt_pk(acc[i][j][0] + bvv[j], acc[i][j][1] + bvv[j]);
        pk.y = cvt_pk(acc[i][j][2] + bvv[j], acc[i][j][3] + bvv[j]);
        *(uint2*)&Vt[(((size_t)b * 16 + h) * 64 + d) * 2048 + l] = pk;
      }
    }
  }
}

// ---------------------------------------------------------------------------
// OUT_f32[M x N] = A_bf16[M x K] * Bt_bf16[N x K]^T + bias_f32. (final proj)
// Same counted-vmcnt pipeline. grid (8, 64), block 256. XCD-swizzled tiles.
// ---------------------------------------------------------------------------
__global__ __launch_bounds__(256) void gemm_bt_bias_f32(
    const unsigned short* __restrict__ A, const unsigned short* __restrict__ Bt,
    const float* __restrict__ bias, float* __restrict__ C,
    int M, int N, int K) {
  __shared__ unsigned short As[2][128 * 32];
  __shared__ unsigned short Bs[2][128 * 32];
  const int tid = threadIdx.x;
  const int wave = tid >> 6;
  const int lane = tid & 63;
  const int fm = lane & 15;
  const int quad = lane >> 4;
  int m0, n0;
  xcd_tiles(blockIdx.x, blockIdx.y, &m0, &n0);
  const int wm = (wave >> 1) * 64;
  const int wn = (wave & 1) * 64;

  floatx4 acc[4][4];
#pragma unroll
  for (int i = 0; i < 4; ++i)
#pragma unroll
    for (int j = 0; j < 4; ++j) acc[i][j] = (floatx4){0.f, 0.f, 0.f, 0.f};

  const int srow = lane >> 2;
  const int scol = (lane & 3) * 8;
  const unsigned short* Ag = A + (size_t)(m0 + wave * 32 + srow) * K + scol;
  const unsigned short* Bg = Bt + (size_t)(n0 + wave * 32 + srow) * K + scol;
  const int stA = wave * 32 * 32;

#pragma unroll
  for (int t = 0; t < 2; ++t) {
    gl_lds16(Ag + t * 32, &As[t][stA]);
    gl_lds16(Ag + t * 32 + (size_t)16 * K, &As[t][stA + 16 * 32]);
    gl_lds16(Bg + t * 32, &Bs[t][stA]);
    gl_lds16(Bg + t * 32 + (size_t)16 * K, &Bs[t][stA + 16 * 32]);
  }

#pragma unroll 1
  for (int t = 0; t < 30; ++t) {
    const int buf = t & 1;
    VWAIT4();
    BAR();
    FENCE();
    short8 a[4], b[4];
#pragma unroll
    for (int i = 0; i < 4; ++i)
      a[i] = *(const short8*)&As[buf][(wm + i * 16 + fm) * 32 + quad * 8];
#pragma unroll
    for (int j = 0; j < 4; ++j)
      b[j] = *(const short8*)&Bs[buf][(wn + j * 16 + fm) * 32 + quad * 8];
#pragma unroll
    for (int i = 0; i < 4; ++i)
#pragma unroll
      for (int j = 0; j < 4; ++j) acc[i][j] = MFMA16(a[i], b[j], acc[i][j]);
    BAR();
    FENCE();
    const int tn = t + 2;
    gl_lds16(Ag + tn * 32, &As[buf][stA]);
    gl_lds16(Ag + tn * 32 + (size_t)16 * K, &As[buf][stA + 16 * 32]);
    gl_lds16(Bg + tn * 32, &Bs[buf][stA]);
    gl_lds16(Bg + tn * 32 + (size_t)16 * K, &Bs[buf][stA + 16 * 32]);
  }
#pragma unroll
  for (int t = 30; t < 32; ++t) {
    if (t == 30) VWAIT4(); else VWAIT0();
    BAR();
    FENCE();
    const int buf = t & 1;
    short8 a[4], b[4];
#pragma unroll
    for (int i = 0; i < 4; ++i)
      a[i] = *(const short8*)&As[buf][(wm + i * 16 + fm) * 32 + quad * 8];
#pragma unroll
    for (int j = 0; j < 4; ++j)
      b[j] = *(const short8*)&Bs[buf][(wn + j * 16 + fm) * 32 + quad * 8];
#pragma unroll
    for (int i = 0; i < 4; ++i)
#pragma unroll
      for (int j = 0; j < 4; ++j) acc[i][j] = MFMA16(a[i], b[j], acc[i][j]);
  }

  float bv[4];
#pragma unroll
  for (int j = 0; j < 4; ++j) bv[j] = bias[n0 + wn + j * 16 + fm];
#pragma unroll
  for (int i = 0; i < 4; ++i) {
    int row = m0 + wm + i * 16 + quad * 4;
#pragma unroll
    for (int j = 0; j < 4; ++j) {
      int col = n0 + wn + j * 16 + fm;
#pragma unroll
      for (int r = 0; r < 4; ++r)
        C[(size_t)(row + r) * N + col] = acc[i][j][r] + bv[j];  // fp32 out
    }
  }
}

// ---------------------------------------------------------------------------
// Flash attention, transposed orientation: S^T = K Q^T, O^T = V^T P^T.
// r10: in-register P redistribution (T12-derived for 16x16 fragments):
// replaces the per-kt P LDS write + threadfence + P LDS read with
// v_permlane32_swap + v_permlane16_swap on cvt_pk'd bf16 pairs.
// Derivation: target lane (fm,quad) B-fragment dwords need c0/c1[jt=2ks+
// (quad>>1)] from source quads {2(quad&1), 2(quad&1)+1}. swap32(c[e],c[o])
// -> P=[e:q01|o:q01], Q=[e:q23|o:q23]; swap16(P,Q) -> R=[e:q0,e:q2,o:q0,
// o:q2]=dw0(dw1), S=[e:q1,e:q3,o:q1,o:q3]=dw2(dw3).
// Freed 18KB P buffer -> Q stages into the K∪V region; LDS 36.9->18.4KB;
// launch_bounds(256,6) -> 6 blocks/CU.
// Kept from r9 (both measured wins): XCD head-locality swizzle (FETCH
// 143->28.7MB) and T5 setprio around MFMA clusters.
// Q PRE-SCALED by log2(e)/sqrt(dk); p = exp2(s) raw v_exp_f32; l on the
// matrix pipe via MFMA(ones, pf). Q/K/X layout [b*2048+l][h*64+d];
// Vt layout [bh*64+d][2048]. X aliases Q. grid (16, 64), block 256.
// ---------------------------------------------------------------------------
__global__ __launch_bounds__(256, 6) void attn_kernel(
    const unsigned short* Qb, const unsigned short* __restrict__ Kb,
    const unsigned short* __restrict__ Vtg, unsigned short* Xb) {
  // LDS (shorts): K [64][72] @0, V [64][72] @4608. Q tile [128][72] stages
  // across the union (rows 0-127) before the kt loop. 18,432 B total.
  __shared__ unsigned short lds[9216];

  const int tid = threadIdx.x;
  const int wave = tid >> 6;
  const int lane = tid & 63;
  const int fm = lane & 15;
  const int quad = lane >> 4;
  // head-locality remap (bijective): flat = bx + by*16 in 0..1023;
  // xcd = flat&7, loc = flat>>3; bh = xcd*8 + (loc>>4); qt = loc&15.
  const int flat = blockIdx.x + (blockIdx.y << 4);
  const int loc = flat >> 3;
  const int qt = loc & 15;
  const int bh = ((flat & 7) << 3) | (loc >> 4);
  const size_t base = (size_t)(bh >> 4) * (LQ * DM) + (size_t)(bh & 15) * 64;
  const unsigned short* Vg = Vtg + (size_t)bh * 64 * 2048;
  const int q0 = qt * 128;

  // stage Q tile [128][64] -> lds[128][72] (union of K and V regions)
#pragma unroll
  for (int it = 0; it < 4; ++it) {
    int idx = it * 256 + tid;
    int r = idx >> 3;
    int cc = (idx & 7) * 8;
    *(short8*)&lds[r * 72 + cc] =
        *(const short8*)(Qb + base + (size_t)(q0 + r) * DM + cc);
  }
  __syncthreads();
  short8 qf[2][2];
#pragma unroll
  for (int mt = 0; mt < 2; ++mt)
#pragma unroll
    for (int ks = 0; ks < 2; ++ks)
      qf[mt][ks] = *(const short8*)&lds[(wave * 32 + mt * 16 + fm) * 72 + ks * 32 + quad * 8];
  __syncthreads();

  // ones fragment for the l-row-sum MFMA (bf16 1.0 = 0x3F80)
  short8 ones;
#pragma unroll
  for (int i = 0; i < 8; ++i) ones[i] = (short)0x3F80;

  floatx4 lacc[2];
  lacc[0] = (floatx4){0.f, 0.f, 0.f, 0.f};
  lacc[1] = (floatx4){0.f, 0.f, 0.f, 0.f};
  floatx4 oacc[4][2];
#pragma unroll
  for (int dt = 0; dt < 4; ++dt)
#pragma unroll
    for (int mt = 0; mt < 2; ++mt) oacc[dt][mt] = (floatx4){0.f, 0.f, 0.f, 0.f};

  const int srow0 = tid >> 3;          // staging row (0..31)
  const int scc = (tid & 7) * 8;       // staging col
  short8 kr[2], vr[2];
#pragma unroll
  for (int it = 0; it < 2; ++it) {
    int row = it * 32 + srow0;
    kr[it] = *(const short8*)(Kb + base + (size_t)row * DM + scc);
    vr[it] = *(const short8*)(Vg + (size_t)row * 2048 + scc);
  }

  for (int kt = 0; kt < 32; ++kt) {
    __syncthreads();  // prior tile's LDS reads complete
#pragma unroll
    for (int it = 0; it < 2; ++it) {
      int row = it * 32 + srow0;
      *(short8*)&lds[row * 72 + scc] = kr[it];          // K
      *(short8*)&lds[4608 + row * 72 + scc] = vr[it];   // V
    }
    __syncthreads();
    if (kt < 31) {
      int k0n = (kt + 1) * 64;
#pragma unroll
      for (int it = 0; it < 2; ++it) {
        int row = it * 32 + srow0;
        kr[it] = *(const short8*)(Kb + base + (size_t)(k0n + row) * DM + scc);
        vr[it] = *(const short8*)(Vg + (size_t)row * 2048 + k0n + scc);
      }
    }

    // S^T = K Q^T : sacc[jt][mt], row=key jt*16+quad*4+r, col=q mt*16+fm
    floatx4 sacc[4][2];
#pragma unroll
    for (int jt = 0; jt < 4; ++jt)
#pragma unroll
      for (int mt = 0; mt < 2; ++mt) sacc[jt][mt] = (floatx4){0.f, 0.f, 0.f, 0.f};
    __builtin_amdgcn_s_setprio(1);
#pragma unroll
    for (int jt = 0; jt < 4; ++jt) {
      short8 k0f = *(const short8*)&lds[(jt * 16 + fm) * 72 + quad * 8];
      short8 k1f = *(const short8*)&lds[(jt * 16 + fm) * 72 + 32 + quad * 8];
#pragma unroll
      for (int mt = 0; mt < 2; ++mt) {
        sacc[jt][mt] = MFMA16(k0f, qf[mt][0], sacc[jt][mt]);
        sacc[jt][mt] = MFMA16(k1f, qf[mt][1], sacc[jt][mt]);
      }
    }
    __builtin_amdgcn_s_setprio(0);

    // softmax numerator: p = exp2(s) (scale pre-folded into Q), then build
    // PV B-fragments ENTIRELY IN REGISTERS via permlane swaps (no LDS P).
    unsigned pfd[2][2][4];  // [ks][mt][dw] — all indices compile-time const
#pragma unroll
    for (int mt = 0; mt < 2; ++mt) {
      unsigned c0[4], c1[4];
#pragma unroll
      for (int jt = 0; jt < 4; ++jt) {
        float p0 = __builtin_amdgcn_exp2f(sacc[jt][mt][0]);
        float p1 = __builtin_amdgcn_exp2f(sacc[jt][mt][1]);
        float p2 = __builtin_amdgcn_exp2f(sacc[jt][mt][2]);
        float p3 = __builtin_amdgcn_exp2f(sacc[jt][mt][3]);
        c0[jt] = cvt_pk(p0, p1);   // keys (4q+0, 4q+1) of 16-block jt
        c1[jt] = cvt_pk(p2, p3);   // keys (4q+2, 4q+3)
      }
#pragma unroll
      for (int ks = 0; ks < 2; ++ks) {
        unsigned a0 = c0[2 * ks], b0 = c0[2 * ks + 1];
        unsigned a1 = c1[2 * ks], b1 = c1[2 * ks + 1];
        // swap32 then swap16: a -> dw0/dw1 (R), b -> dw2/dw3 (S)
        asm("v_permlane32_swap_b32 %0, %1" : "+v"(a0), "+v"(b0));
        asm("v_permlane16_swap_b32 %0, %1" : "+v"(a0), "+v"(b0));
        asm("v_permlane32_swap_b32 %0, %1" : "+v"(a1), "+v"(b1));
        asm("v_permlane16_swap_b32 %0, %1" : "+v"(a1), "+v"(b1));
        pfd[ks][mt][0] = a0;
        pfd[ks][mt][1] = a1;
        pfd[ks][mt][2] = b0;
        pfd[ks][mt][3] = b1;
      }
    }

    // O^T += V^T P^T ; l += ones * P^T (row-sum on the matrix pipe)
    __builtin_amdgcn_s_setprio(1);
#pragma unroll
    for (int ks = 0; ks < 2; ++ks) {
      short8 pf0, pf1;
      {
        union { uint4 u; short8 s; } t;
        t.u = make_uint4(pfd[ks][0][0], pfd[ks][0][1], pfd[ks][0][2], pfd[ks][0][3]);
        pf0 = t.s;
      }
      {
        union { uint4 u; short8 s; } t;
        t.u = make_uint4(pfd[ks][1][0], pfd[ks][1][1], pfd[ks][1][2], pfd[ks][1][3]);
        pf1 = t.s;
      }
      lacc[0] = MFMA16(ones, pf0, lacc[0]);
      lacc[1] = MFMA16(ones, pf1, lacc[1]);
#pragma unroll
      for (int dt = 0; dt < 4; ++dt) {
        short8 vf = *(const short8*)&lds[4608 + (dt * 16 + fm) * 72 + ks * 32 + quad * 8];
        oacc[dt][0] = MFMA16(vf, pf0, oacc[dt][0]);
        oacc[dt][1] = MFMA16(vf, pf1, oacc[dt][1]);
      }
    }
    __builtin_amdgcn_s_setprio(0);
  }

  // lacc rows are all identical (=l[q=fm]); take reg 0, no cross-lane needed.
  float inv[2];
  inv[0] = 1.0f / lacc[0][0];
  inv[1] = 1.0f / lacc[1][0];

  // store: O^T[d=dt*16+quad*4+r][q=mt*16+fm]
#pragma unroll
  for (int mt = 0; mt < 2; ++mt) {
    int q = q0 + wave * 32 + mt * 16 + fm;
#pragma unroll
    for (int dt = 0; dt < 4; ++dt) {
      uint2 o;
      o.x = cvt_pk(oacc[dt][mt][0] * inv[mt], oacc[dt][mt][1] * inv[mt]);
      o.y = cvt_pk(oacc[dt][mt][2] * inv[mt], oacc[dt][mt][3] * inv[mt]);
      *(uint2*)&Xb[base + (size_t)q * DM + dt * 16 + quad * 4] = o;
    }
  }
}

// ---------------------------------------------------------------------------
extern "C" void kernel_launch(void* const* d_in, const int* in_sizes, int n_in,
                              void* d_out, int out_size, void* d_ws, size_t ws_size,
                              hipStream_t stream) {
  const float* q_in = (const float*)d_in[0];
  const float* k_in = (const float*)d_in[1];
  const float* v_in = (const float*)d_in[2];
  const float* Wq = (const float*)d_in[3];
  const float* bq = (const float*)d_in[4];
  const float* Wk = (const float*)d_in[5];
  const float* bk = (const float*)d_in[6];
  const float* Wv = (const float*)d_in[7];
  const float* bv = (const float*)d_in[8];
  const float* Wo = (const float*)d_in[9];
  const float* bo = (const float*)d_in[10];
  float* out = (float*)d_out;

  char* w = (char*)d_ws;
  unsigned short* WqT = (unsigned short*)w; w += 1024 * 1024 * 2;
  unsigned short* WkT = (unsigned short*)w; w += 1024 * 1024 * 2;
  unsigned short* WvT = (unsigned short*)w; w += 1024 * 1024 * 2;
  unsigned short* WoT = (unsigned short*)w; w += 1024 * 1024 * 2;
  unsigned short* Qb  = (unsigned short*)w; w += (size_t)8192 * 1024 * 2;
  unsigned short* Kb  = (unsigned short*)w; w += (size_t)8192 * 1024 * 2;
  unsigned short* Vt  = (unsigned short*)w; w += (size_t)8192 * 1024 * 2;
  unsigned short* Qa  = (unsigned short*)w; w += (size_t)8192 * 1024 * 2;
  unsigned short* Ka  = (unsigned short*)w; w += (size_t)8192 * 1024 * 2;
  unsigned short* Va  = (unsigned short*)w; w += (size_t)8192 * 1024 * 2;
  unsigned short* Xb  = Qb;  // attention output aliases Q (validated r2 vs r3)

  transpose_w4<<<dim3(16, 16, 4), 256, 0, stream>>>(Wq, Wk, Wv, Wo,
                                                    WqT, WkT, WvT, WoT);

  cvt3<<<dim3(4096, 1, 3), 256, 0, stream>>>(q_in, k_in, v_in, Qa, Ka, Va);

  gemm_qkv<<<dim3(8, 64, 3), 256, 0, stream>>>(
      Qa, Ka, Va, WqT, WkT, WvT, bq, bk, bv, Qb, Kb, Vt);

  attn_kernel<<<dim3(16, 64), 256, 0, stream>>>(Qb, Kb, Vt, Xb);

  gemm_bt_bias_f32<<<dim3(8, 64), 256, 0, stream>>>(Xb, WoT, bo, out, 8192, 1024, 1024);
}

// Round 13
// 344.400 us; speedup vs baseline: 2.1485x; 2.1485x over previous
//
#include <hip/hip_runtime.h>
#include <hip/hip_bf16.h>

#define DM 1024   // model dim
#define LQ 2048   // sequence length

typedef __attribute__((ext_vector_type(8))) short short8;
typedef __attribute__((ext_vector_type(4))) float floatx4;
typedef __attribute__((ext_vector_type(2))) unsigned uintx2;

#define MFMA16(a, b, c) __builtin_amdgcn_mfma_f32_16x16x32_bf16((a), (b), (c), 0, 0, 0)
#define BAR() __builtin_amdgcn_s_barrier()
#define FENCE() asm volatile("" ::: "memory")
#define VWAIT4() asm volatile("s_waitcnt vmcnt(4)" ::: "memory")
#define VWAIT0() asm volatile("s_waitcnt vmcnt(0)" ::: "memory")

__device__ __forceinline__ unsigned short f2b(float f) {
  union { float f; unsigned u; } x; x.f = f;
  unsigned u = x.u;
  unsigned r = (u + 0x7fffu + ((u >> 16) & 1u)) >> 16;  // RNE
  return (unsigned short)r;
}

// pack two fp32 -> bf16x2 in ONE instruction (HW RNE).
__device__ __forceinline__ unsigned cvt_pk(float lo, float hi) {
  unsigned r;
  asm("v_cvt_pk_bf16_f32 %0, %1, %2" : "=v"(r) : "v"(lo), "v"(hi));
  return r;
}
__device__ __forceinline__ uint4 pack16(float4 a, float4 b) {
  return make_uint4(cvt_pk(a.x, a.y), cvt_pk(a.z, a.w),
                    cvt_pk(b.x, b.y), cvt_pk(b.z, b.w));
}

// async global->LDS, 16B per lane; LDS dest = wave-uniform base + lane*16
__device__ __forceinline__ void gl_lds16(const void* g, void* l) {
  __builtin_amdgcn_global_load_lds(
      (const __attribute__((address_space(1))) void*)g,
      (__attribute__((address_space(3))) void*)l, 16, 0, 0);
}

// XCD-aware tile remap for 64 m-tiles x 8 n-tiles grids (gridDim.x == 8).
// r1 result: FETCH 397->82 MB (confirmed L2-reuse mechanism).
__device__ __forceinline__ void xcd_tiles(int bx, int by, int* m0, int* n0) {
  int flat = bx + (by << 3);
  int xcd = flat & 7;
  int loc = flat >> 3;
  *m0 = (xcd * 8 + (loc >> 3)) * 128;
  *n0 = (loc & 7) * 128;
}

// ---------------------------------------------------------------------------
// fp32 -> bf16 conversion of the three activation inputs (one-time pass).
// grid (4096,1,3).
// ---------------------------------------------------------------------------
__global__ __launch_bounds__(256) void cvt3(
    const float* __restrict__ A0, const float* __restrict__ A1,
    const float* __restrict__ A2,
    unsigned short* __restrict__ O0, unsigned short* __restrict__ O1,
    unsigned short* __restrict__ O2) {
  const float* s = (blockIdx.z == 0) ? A0 : (blockIdx.z == 1) ? A1 : A2;
  unsigned short* d = (blockIdx.z == 0) ? O0 : (blockIdx.z == 1) ? O1 : O2;
  size_t i = ((size_t)blockIdx.x * 256 + threadIdx.x) * 8;
  float4 f0 = *(const float4*)(s + i);
  float4 f1 = *(const float4*)(s + i + 4);
  *(uint4*)(d + i) = pack16(f0, f1);
}

// ---------------------------------------------------------------------------
// 4 weight transposes in one dispatch: dst[n][k] = bf16(src[k][n]), 1024x1024
// grid (16,16,4)
// ---------------------------------------------------------------------------
__global__ __launch_bounds__(256) void transpose_w4(
    const float* __restrict__ W0, const float* __restrict__ W1,
    const float* __restrict__ W2, const float* __restrict__ W3,
    unsigned short* __restrict__ T0, unsigned short* __restrict__ T1,
    unsigned short* __restrict__ T2, unsigned short* __restrict__ T3) {
  __shared__ unsigned short t[64][65];
  const float* src; unsigned short* dst;
  switch (blockIdx.z) {
    case 0: src = W0; dst = T0; break;
    case 1: src = W1; dst = T1; break;
    case 2: src = W2; dst = T2; break;
    default: src = W3; dst = T3; break;
  }
  const int x = threadIdx.x & 63;
  const int y4 = threadIdx.x >> 6;
  const int c0 = blockIdx.x * 64;
  const int r0 = blockIdx.y * 64;
#pragma unroll
  for (int i = 0; i < 16; ++i) {
    int r = y4 * 16 + i;
    t[r][x] = f2b(src[(size_t)(r0 + r) * 1024 + c0 + x]);
  }
  __syncthreads();
#pragma unroll
  for (int i = 0; i < 16; ++i) {
    int r = y4 * 16 + i;
    dst[(size_t)(c0 + r) * 1024 + r0 + x] = t[x][r];
  }
}

// ---------------------------------------------------------------------------
// Counted-vmcnt K-loop (T4, m218), verified r5. r4 lesson: no LDS pointer
// arrays on gfx950 — index __shared__ arrays directly.
// ---------------------------------------------------------------------------

// ---------------------------------------------------------------------------
// Batched QKV projection from PRE-CONVERTED bf16 activations.
// z=0 -> Qb (pre-scaled by log2(e)/sqrt(dk)), z=1 -> Kb, z=2 -> Vt
// (transposed layout Vt[(b*16+h)*64+d][l]).
// grid (8, 64, 3), block 256. XCD-swizzled tiles.
// ---------------------------------------------------------------------------
__global__ __launch_bounds__(256) void gemm_qkv(
    const unsigned short* __restrict__ Aq, const unsigned short* __restrict__ Ak,
    const unsigned short* __restrict__ Av,
    const unsigned short* __restrict__ BtQ, const unsigned short* __restrict__ BtK,
    const unsigned short* __restrict__ BtV,
    const float* __restrict__ bq, const float* __restrict__ bk,
    const float* __restrict__ bv,
    unsigned short* __restrict__ Qb, unsigned short* __restrict__ Kb,
    unsigned short* __restrict__ Vt) {
  const int K = 1024, N = 1024;
  __shared__ unsigned short As[2][128 * 32];
  __shared__ unsigned short Bs[2][128 * 32];
  const int z = blockIdx.z;
  const unsigned short* A; const unsigned short* Bt; const float* bias;
  if (z == 0) { A = Aq; Bt = BtQ; bias = bq; }
  else if (z == 1) { A = Ak; Bt = BtK; bias = bk; }
  else { A = Av; Bt = BtV; bias = bv; }

  const int tid = threadIdx.x;
  const int wave = tid >> 6;
  const int lane = tid & 63;
  const int fm = lane & 15;
  const int quad = lane >> 4;
  int m0, n0;
  xcd_tiles(blockIdx.x, blockIdx.y, &m0, &n0);
  const int wm = (wave >> 1) * 64;
  const int wn = (wave & 1) * 64;

  floatx4 acc[4][4];
#pragma unroll
  for (int i = 0; i < 4; ++i)
#pragma unroll
    for (int j = 0; j < 4; ++j) acc[i][j] = (floatx4){0.f, 0.f, 0.f, 0.f};

  const int srow = lane >> 2;       // 0..15
  const int scol = (lane & 3) * 8;  // 0,8,16,24 (shorts; 16B per lane)
  const unsigned short* Ag = A + (size_t)(m0 + wave * 32 + srow) * K + scol;
  const unsigned short* Bg = Bt + (size_t)(n0 + wave * 32 + srow) * K + scol;
  const int stA = wave * 32 * 32;

  // prologue: stage tiles 0 and 1 (8 loads outstanding per wave)
#pragma unroll
  for (int t = 0; t < 2; ++t) {
    gl_lds16(Ag + t * 32, &As[t][stA]);
    gl_lds16(Ag + t * 32 + (size_t)16 * K, &As[t][stA + 16 * 32]);
    gl_lds16(Bg + t * 32, &Bs[t][stA]);
    gl_lds16(Bg + t * 32 + (size_t)16 * K, &Bs[t][stA + 16 * 32]);
  }

#pragma unroll 1
  for (int t = 0; t < 30; ++t) {
    const int buf = t & 1;
    VWAIT4();            // tile t's 4 loads done; t+1's stay in flight
    BAR();
    FENCE();
    short8 a[4], b[4];
#pragma unroll
    for (int i = 0; i < 4; ++i)
      a[i] = *(const short8*)&As[buf][(wm + i * 16 + fm) * 32 + quad * 8];
#pragma unroll
    for (int j = 0; j < 4; ++j)
      b[j] = *(const short8*)&Bs[buf][(wn + j * 16 + fm) * 32 + quad * 8];
#pragma unroll
    for (int i = 0; i < 4; ++i)
#pragma unroll
      for (int j = 0; j < 4; ++j) acc[i][j] = MFMA16(a[i], b[j], acc[i][j]);
    BAR();               // all waves done reading buf
    FENCE();
    const int tn = t + 2;
    gl_lds16(Ag + tn * 32, &As[buf][stA]);
    gl_lds16(Ag + tn * 32 + (size_t)16 * K, &As[buf][stA + 16 * 32]);
    gl_lds16(Bg + tn * 32, &Bs[buf][stA]);
    gl_lds16(Bg + tn * 32 + (size_t)16 * K, &Bs[buf][stA + 16 * 32]);
  }
  // peeled tails: t=30 (buf 0), t=31 (buf 1); no more staging
#pragma unroll
  for (int t = 30; t < 32; ++t) {
    if (t == 30) VWAIT4(); else VWAIT0();
    BAR();
    FENCE();
    const int buf = t & 1;
    short8 a[4], b[4];
#pragma unroll
    for (int i = 0; i < 4; ++i)
      a[i] = *(const short8*)&As[buf][(wm + i * 16 + fm) * 32 + quad * 8];
#pragma unroll
    for (int j = 0; j < 4; ++j)
      b[j] = *(const short8*)&Bs[buf][(wn + j * 16 + fm) * 32 + quad * 8];
#pragma unroll
    for (int i = 0; i < 4; ++i)
#pragma unroll
      for (int j = 0; j < 4; ++j) acc[i][j] = MFMA16(a[i], b[j], acc[i][j]);
  }

  float bvv[4];
#pragma unroll
  for (int j = 0; j < 4; ++j) bvv[j] = bias[n0 + wn + j * 16 + fm];

  if (z < 2) {
    // Q is pre-scaled by log2(e)/sqrt(dk) so attn's exp2 needs no multiply.
    const float sc = (z == 0) ? 0.1803368801111204f : 1.0f;
    unsigned short* C = (z == 0) ? Qb : Kb;
#pragma unroll
    for (int i = 0; i < 4; ++i) {
      int row = m0 + wm + i * 16 + quad * 4;
#pragma unroll
      for (int j = 0; j < 4; ++j) {
        int col = n0 + wn + j * 16 + fm;
#pragma unroll
        for (int r = 0; r < 4; ++r)
          C[(size_t)(row + r) * N + col] = f2b((acc[i][j][r] + bvv[j]) * sc);
      }
    }
  } else {
    // transposed: Vt[((b*16+h)*64+d)][l]
#pragma unroll
    for (int i = 0; i < 4; ++i) {
      int row = m0 + wm + i * 16 + quad * 4;
      int b = row >> 11, l = row & 2047;
#pragma unroll
      for (int j = 0; j < 4; ++j) {
        int col = n0 + wn + j * 16 + fm;
        int h = col >> 6, d = col & 63;
        uint2 pk;
        pk.x = cvt_pk(acc[i][j][0] + bvv[j], acc[i][j][1] + bvv[j]);
        pk.y = cvt_pk(acc[i][j][2] + bvv[j], acc[i][j][3] + bvv[j]);
        *(uint2*)&Vt[(((size_t)b * 16 + h) * 64 + d) * 2048 + l] = pk;
      }
    }
  }
}

// ---------------------------------------------------------------------------
// OUT_f32[M x N] = A_bf16[M x K] * Bt_bf16[N x K]^T + bias_f32. (final proj)
// Same counted-vmcnt pipeline. grid (8, 64), block 256. XCD-swizzled tiles.
// ---------------------------------------------------------------------------
__global__ __launch_bounds__(256) void gemm_bt_bias_f32(
    const unsigned short* __restrict__ A, const unsigned short* __restrict__ Bt,
    const float* __restrict__ bias, float* __restrict__ C,
    int M, int N, int K) {
  __shared__ unsigned short As[2][128 * 32];
  __shared__ unsigned short Bs[2][128 * 32];
  const int tid = threadIdx.x;
  const int wave = tid >> 6;
  const int lane = tid & 63;
  const int fm = lane & 15;
  const int quad = lane >> 4;
  int m0, n0;
  xcd_tiles(blockIdx.x, blockIdx.y, &m0, &n0);
  const int wm = (wave >> 1) * 64;
  const int wn = (wave & 1) * 64;

  floatx4 acc[4][4];
#pragma unroll
  for (int i = 0; i < 4; ++i)
#pragma unroll
    for (int j = 0; j < 4; ++j) acc[i][j] = (floatx4){0.f, 0.f, 0.f, 0.f};

  const int srow = lane >> 2;
  const int scol = (lane & 3) * 8;
  const unsigned short* Ag = A + (size_t)(m0 + wave * 32 + srow) * K + scol;
  const unsigned short* Bg = Bt + (size_t)(n0 + wave * 32 + srow) * K + scol;
  const int stA = wave * 32 * 32;

#pragma unroll
  for (int t = 0; t < 2; ++t) {
    gl_lds16(Ag + t * 32, &As[t][stA]);
    gl_lds16(Ag + t * 32 + (size_t)16 * K, &As[t][stA + 16 * 32]);
    gl_lds16(Bg + t * 32, &Bs[t][stA]);
    gl_lds16(Bg + t * 32 + (size_t)16 * K, &Bs[t][stA + 16 * 32]);
  }

#pragma unroll 1
  for (int t = 0; t < 30; ++t) {
    const int buf = t & 1;
    VWAIT4();
    BAR();
    FENCE();
    short8 a[4], b[4];
#pragma unroll
    for (int i = 0; i < 4; ++i)
      a[i] = *(const short8*)&As[buf][(wm + i * 16 + fm) * 32 + quad * 8];
#pragma unroll
    for (int j = 0; j < 4; ++j)
      b[j] = *(const short8*)&Bs[buf][(wn + j * 16 + fm) * 32 + quad * 8];
#pragma unroll
    for (int i = 0; i < 4; ++i)
#pragma unroll
      for (int j = 0; j < 4; ++j) acc[i][j] = MFMA16(a[i], b[j], acc[i][j]);
    BAR();
    FENCE();
    const int tn = t + 2;
    gl_lds16(Ag + tn * 32, &As[buf][stA]);
    gl_lds16(Ag + tn * 32 + (size_t)16 * K, &As[buf][stA + 16 * 32]);
    gl_lds16(Bg + tn * 32, &Bs[buf][stA]);
    gl_lds16(Bg + tn * 32 + (size_t)16 * K, &Bs[buf][stA + 16 * 32]);
  }
#pragma unroll
  for (int t = 30; t < 32; ++t) {
    if (t == 30) VWAIT4(); else VWAIT0();
    BAR();
    FENCE();
    const int buf = t & 1;
    short8 a[4], b[4];
#pragma unroll
    for (int i = 0; i < 4; ++i)
      a[i] = *(const short8*)&As[buf][(wm + i * 16 + fm) * 32 + quad * 8];
#pragma unroll
    for (int j = 0; j < 4; ++j)
      b[j] = *(const short8*)&Bs[buf][(wn + j * 16 + fm) * 32 + quad * 8];
#pragma unroll
    for (int i = 0; i < 4; ++i)
#pragma unroll
      for (int j = 0; j < 4; ++j) acc[i][j] = MFMA16(a[i], b[j], acc[i][j]);
  }

  float bv[4];
#pragma unroll
  for (int j = 0; j < 4; ++j) bv[j] = bias[n0 + wn + j * 16 + fm];
#pragma unroll
  for (int i = 0; i < 4; ++i) {
    int row = m0 + wm + i * 16 + quad * 4;
#pragma unroll
    for (int j = 0; j < 4; ++j) {
      int col = n0 + wn + j * 16 + fm;
#pragma unroll
      for (int r = 0; r < 4; ++r)
        C[(size_t)(row + r) * N + col] = acc[i][j][r] + bv[j];  // fp32 out
    }
  }
}

// ---------------------------------------------------------------------------
// Flash attention, transposed orientation: S^T = K Q^T, O^T = V^T P^T.
// r12 = r10's attn body VERBATIM (the permlane dataflow that PASSED with
// absmax 4.88e-4) with exactly two changes:
//   1. launch_bounds(256,4): r10's (256,6) capped VGPR at ~85 vs ~130 live
//      -> 2.3GB scratch spill, 485us. Cap 128 is the r9-proven setting.
//   2. permlane swaps via __builtin_amdgcn_permlane{32,16}_swap instead of
//      inline asm. r11's failure analysis: identical dataflow to r10 but
//      no spill -> cvt_pk(asm) and permlane(asm) became adjacent -> a
//      VALU-write->permlane-read hazard the compiler cannot see inside
//      OPAQUE asm produced stale lanes (small 8.6e-3 error). r10 passed
//      only because spill code spaced them. The builtins let the hazard
//      recognizer insert the required waits.
// Kept: XCD head-locality swizzle (FETCH 143->28.7MB), T5 setprio, 18.4KB
// LDS (K/V only; Q stages into their union).
// Q PRE-SCALED by log2(e)/sqrt(dk); p = exp2(s) raw v_exp_f32; l on the
// matrix pipe via MFMA(ones, pf). Q/K/X layout [b*2048+l][h*64+d];
// Vt layout [bh*64+d][2048]. X aliases Q. grid (16, 64), block 256.
// ---------------------------------------------------------------------------
__global__ __launch_bounds__(256, 4) void attn_kernel(
    const unsigned short* Qb, const unsigned short* __restrict__ Kb,
    const unsigned short* __restrict__ Vtg, unsigned short* Xb) {
  // LDS (shorts): K [64][72] @0, V [64][72] @4608. Q tile [128][72] stages
  // across the union (rows 0-127) before the kt loop. 18,432 B total.
  __shared__ unsigned short lds[9216];

  const int tid = threadIdx.x;
  const int wave = tid >> 6;
  const int lane = tid & 63;
  const int fm = lane & 15;
  const int quad = lane >> 4;
  // head-locality remap (bijective): flat = bx + by*16 in 0..1023;
  // xcd = flat&7, loc = flat>>3; bh = xcd*8 + (loc>>4); qt = loc&15.
  const int flat = blockIdx.x + (blockIdx.y << 4);
  const int loc = flat >> 3;
  const int qt = loc & 15;
  const int bh = ((flat & 7) << 3) | (loc >> 4);
  const size_t base = (size_t)(bh >> 4) * (LQ * DM) + (size_t)(bh & 15) * 64;
  const unsigned short* Vg = Vtg + (size_t)bh * 64 * 2048;
  const int q0 = qt * 128;

  // stage Q tile [128][64] -> lds[128][72] (union of K and V regions)
#pragma unroll
  for (int it = 0; it < 4; ++it) {
    int idx = it * 256 + tid;
    int r = idx >> 3;
    int cc = (idx & 7) * 8;
    *(short8*)&lds[r * 72 + cc] =
        *(const short8*)(Qb + base + (size_t)(q0 + r) * DM + cc);
  }
  __syncthreads();
  short8 qf[2][2];
#pragma unroll
  for (int mt = 0; mt < 2; ++mt)
#pragma unroll
    for (int ks = 0; ks < 2; ++ks)
      qf[mt][ks] = *(const short8*)&lds[(wave * 32 + mt * 16 + fm) * 72 + ks * 32 + quad * 8];
  __syncthreads();

  // ones fragment for the l-row-sum MFMA (bf16 1.0 = 0x3F80)
  short8 ones;
#pragma unroll
  for (int i = 0; i < 8; ++i) ones[i] = (short)0x3F80;

  floatx4 lacc[2];
  lacc[0] = (floatx4){0.f, 0.f, 0.f, 0.f};
  lacc[1] = (floatx4){0.f, 0.f, 0.f, 0.f};
  floatx4 oacc[4][2];
#pragma unroll
  for (int dt = 0; dt < 4; ++dt)
#pragma unroll
    for (int mt = 0; mt < 2; ++mt) oacc[dt][mt] = (floatx4){0.f, 0.f, 0.f, 0.f};

  const int srow0 = tid >> 3;          // staging row (0..31)
  const int scc = (tid & 7) * 8;       // staging col
  short8 kr[2], vr[2];
#pragma unroll
  for (int it = 0; it < 2; ++it) {
    int row = it * 32 + srow0;
    kr[it] = *(const short8*)(Kb + base + (size_t)row * DM + scc);
    vr[it] = *(const short8*)(Vg + (size_t)row * 2048 + scc);
  }

  for (int kt = 0; kt < 32; ++kt) {
    __syncthreads();  // prior tile's LDS reads complete
#pragma unroll
    for (int it = 0; it < 2; ++it) {
      int row = it * 32 + srow0;
      *(short8*)&lds[row * 72 + scc] = kr[it];          // K
      *(short8*)&lds[4608 + row * 72 + scc] = vr[it];   // V
    }
    __syncthreads();
    if (kt < 31) {
      int k0n = (kt + 1) * 64;
#pragma unroll
      for (int it = 0; it < 2; ++it) {
        int row = it * 32 + srow0;
        kr[it] = *(const short8*)(Kb + base + (size_t)(k0n + row) * DM + scc);
        vr[it] = *(const short8*)(Vg + (size_t)row * 2048 + k0n + scc);
      }
    }

    // S^T = K Q^T : sacc[jt][mt], row=key jt*16+quad*4+r, col=q mt*16+fm
    floatx4 sacc[4][2];
#pragma unroll
    for (int jt = 0; jt < 4; ++jt)
#pragma unroll
      for (int mt = 0; mt < 2; ++mt) sacc[jt][mt] = (floatx4){0.f, 0.f, 0.f, 0.f};
    __builtin_amdgcn_s_setprio(1);
#pragma unroll
    for (int jt = 0; jt < 4; ++jt) {
      short8 k0f = *(const short8*)&lds[(jt * 16 + fm) * 72 + quad * 8];
      short8 k1f = *(const short8*)&lds[(jt * 16 + fm) * 72 + 32 + quad * 8];
#pragma unroll
      for (int mt = 0; mt < 2; ++mt) {
        sacc[jt][mt] = MFMA16(k0f, qf[mt][0], sacc[jt][mt]);
        sacc[jt][mt] = MFMA16(k1f, qf[mt][1], sacc[jt][mt]);
      }
    }
    __builtin_amdgcn_s_setprio(0);

    // softmax numerator: p = exp2(s) (scale pre-folded into Q), then build
    // PV B-fragments ENTIRELY IN REGISTERS via permlane swap BUILTINS.
    unsigned pfd[2][2][4];  // [ks][mt][dw] — all indices compile-time const
#pragma unroll
    for (int mt = 0; mt < 2; ++mt) {
      unsigned c0[4], c1[4];
#pragma unroll
      for (int jt = 0; jt < 4; ++jt) {
        float p0 = __builtin_amdgcn_exp2f(sacc[jt][mt][0]);
        float p1 = __builtin_amdgcn_exp2f(sacc[jt][mt][1]);
        float p2 = __builtin_amdgcn_exp2f(sacc[jt][mt][2]);
        float p3 = __builtin_amdgcn_exp2f(sacc[jt][mt][3]);
        c0[jt] = cvt_pk(p0, p1);   // keys (4q+0, 4q+1) of 16-block jt
        c1[jt] = cvt_pk(p2, p3);   // keys (4q+2, 4q+3)
      }
#pragma unroll
      for (int ks = 0; ks < 2; ++ks) {
        unsigned a0 = c0[2 * ks], b0 = c0[2 * ks + 1];
        unsigned a1 = c1[2 * ks], b1 = c1[2 * ks + 1];
        // swap32 then swap16: a -> dw0/dw1 (R), b -> dw2/dw3 (S)
        uintx2 r;
        r = __builtin_amdgcn_permlane32_swap(a0, b0, false, false);
        a0 = r[0]; b0 = r[1];
        r = __builtin_amdgcn_permlane16_swap(a0, b0, false, false);
        a0 = r[0]; b0 = r[1];
        r = __builtin_amdgcn_permlane32_swap(a1, b1, false, false);
        a1 = r[0]; b1 = r[1];
        r = __builtin_amdgcn_permlane16_swap(a1, b1, false, false);
        a1 = r[0]; b1 = r[1];
        pfd[ks][mt][0] = a0;
        pfd[ks][mt][1] = a1;
        pfd[ks][mt][2] = b0;
        pfd[ks][mt][3] = b1;
      }
    }

    // O^T += V^T P^T ; l += ones * P^T (row-sum on the matrix pipe)
    __builtin_amdgcn_s_setprio(1);
#pragma unroll
    for (int ks = 0; ks < 2; ++ks) {
      short8 pf0, pf1;
      {
        union { uint4 u; short8 s; } t;
        t.u = make_uint4(pfd[ks][0][0], pfd[ks][0][1], pfd[ks][0][2], pfd[ks][0][3]);
        pf0 = t.s;
      }
      {
        union { uint4 u; short8 s; } t;
        t.u = make_uint4(pfd[ks][1][0], pfd[ks][1][1], pfd[ks][1][2], pfd[ks][1][3]);
        pf1 = t.s;
      }
      lacc[0] = MFMA16(ones, pf0, lacc[0]);
      lacc[1] = MFMA16(ones, pf1, lacc[1]);
#pragma unroll
      for (int dt = 0; dt < 4; ++dt) {
        short8 vf = *(const short8*)&lds[4608 + (dt * 16 + fm) * 72 + ks * 32 + quad * 8];
        oacc[dt][0] = MFMA16(vf, pf0, oacc[dt][0]);
        oacc[dt][1] = MFMA16(vf, pf1, oacc[dt][1]);
      }
    }
    __builtin_amdgcn_s_setprio(0);
  }

  // lacc rows are all identical (=l[q=fm]); take reg 0, no cross-lane needed.
  float inv[2];
  inv[0] = 1.0f / lacc[0][0];
  inv[1] = 1.0f / lacc[1][0];

  // store: O^T[d=dt*16+quad*4+r][q=mt*16+fm]
#pragma unroll
  for (int mt = 0; mt < 2; ++mt) {
    int q = q0 + wave * 32 + mt * 16 + fm;
#pragma unroll
    for (int dt = 0; dt < 4; ++dt) {
      uint2 o;
      o.x = cvt_pk(oacc[dt][mt][0] * inv[mt], oacc[dt][mt][1] * inv[mt]);
      o.y = cvt_pk(oacc[dt][mt][2] * inv[mt], oacc[dt][mt][3] * inv[mt]);
      *(uint2*)&Xb[base + (size_t)q * DM + dt * 16 + quad * 4] = o;
    }
  }
}

// ---------------------------------------------------------------------------
extern "C" void kernel_launch(void* const* d_in, const int* in_sizes, int n_in,
                              void* d_out, int out_size, void* d_ws, size_t ws_size,
                              hipStream_t stream) {
  const float* q_in = (const float*)d_in[0];
  const float* k_in = (const float*)d_in[1];
  const float* v_in = (const float*)d_in[2];
  const float* Wq = (const float*)d_in[3];
  const float* bq = (const float*)d_in[4];
  const float* Wk = (const float*)d_in[5];
  const float* bk = (const float*)d_in[6];
  const float* Wv = (const float*)d_in[7];
  const float* bv = (const float*)d_in[8];
  const float* Wo = (const float*)d_in[9];
  const float* bo = (const float*)d_in[10];
  float* out = (float*)d_out;

  char* w = (char*)d_ws;
  unsigned short* WqT = (unsigned short*)w; w += 1024 * 1024 * 2;
  unsigned short* WkT = (unsigned short*)w; w += 1024 * 1024 * 2;
  unsigned short* WvT = (unsigned short*)w; w += 1024 * 1024 * 2;
  unsigned short* WoT = (unsigned short*)w; w += 1024 * 1024 * 2;
  unsigned short* Qb  = (unsigned short*)w; w += (size_t)8192 * 1024 * 2;
  unsigned short* Kb  = (unsigned short*)w; w += (size_t)8192 * 1024 * 2;
  unsigned short* Vt  = (unsigned short*)w; w += (size_t)8192 * 1024 * 2;
  unsigned short* Qa  = (unsigned short*)w; w += (size_t)8192 * 1024 * 2;
  unsigned short* Ka  = (unsigned short*)w; w += (size_t)8192 * 1024 * 2;
  unsigned short* Va  = (unsigned short*)w; w += (size_t)8192 * 1024 * 2;
  unsigned short* Xb  = Qb;  // attention output aliases Q (validated r2 vs r3)

  transpose_w4<<<dim3(16, 16, 4), 256, 0, stream>>>(Wq, Wk, Wv, Wo,
                                                    WqT, WkT, WvT, WoT);

  cvt3<<<dim3(4096, 1, 3), 256, 0, stream>>>(q_in, k_in, v_in, Qa, Ka, Va);

  gemm_qkv<<<dim3(8, 64, 3), 256, 0, stream>>>(
      Qa, Ka, Va, WqT, WkT, WvT, bq, bk, bv, Qb, Kb, Vt);

  attn_kernel<<<dim3(16, 64), 256, 0, stream>>>(Qb, Kb, Vt, Xb);

  gemm_bt_bias_f32<<<dim3(8, 64), 256, 0, stream>>>(Xb, WoT, bo, out, 8192, 1024, 1024);
}